// Round 7
// baseline (553.837 us; speedup 1.0000x reference)
//
#include <hip/hip_runtime.h>

#define TT 2048
#define BB 8
#define DD 1024
#define NN 64
#define CH 32              // timesteps staged per LDS chunk (scan)
#define NCH (TT / CH)

typedef __attribute__((ext_vector_type(8))) short bfrag;    // 8 bf16 (4 VGPRs)
typedef __attribute__((ext_vector_type(4))) float f32x4;    // MFMA C/D
typedef __attribute__((ext_vector_type(8))) unsigned short ushort8;

__device__ __forceinline__ float sigmoidf_(float x) {
    return 1.0f / (1.0f + __expf(-x));
}

// f32 -> bf16 round-to-nearest-even
__device__ __forceinline__ unsigned short cvt_bf16(float f) {
    unsigned int u = __float_as_uint(f);
    return (unsigned short)((u + 0x7FFF + ((u >> 16) & 1)) >> 16);
}

template <int CTRL>
__device__ __forceinline__ float dpp_add(float x) {
    return x + __int_as_float(__builtin_amdgcn_update_dpp(
        0, __float_as_int(x), CTRL, 0xF, 0xF, true));
}
// Full-wave (64-lane) sum. After 4 within-row stages every 16-lane row holds
// its row sum; row_bcast15 (0x142) adds row0->row1, row2->row3; row_bcast31
// (0x143) adds lane31 (= sum of rows 0+1) into rows 2,3. Lanes 48-63 then
// hold the full 64-lane total. (bound_ctrl=1: sourceless lanes add 0.)
__device__ __forceinline__ float reduce64_hi(float x) {
    x = dpp_add<0xB1>(x);   // quad_perm xor 1
    x = dpp_add<0x4E>(x);   // quad_perm xor 2
    x = dpp_add<0x141>(x);  // row_half_mirror (xor 4)
    x = dpp_add<0x140>(x);  // row_mirror      (xor 8)
    x = dpp_add<0x142>(x);  // row_bcast15
    x = dpp_add<0x143>(x);  // row_bcast31 -> total in lanes 48..63
    return x;
}
__device__ __forceinline__ float bcast63(float x) {
    return __int_as_float(__builtin_amdgcn_readlane(__float_as_int(x), 63));
}

// async global->LDS, 16 B/lane
__device__ __forceinline__ void gll16(const float* g, float* l) {
    __builtin_amdgcn_global_load_lds(
        (const __attribute__((address_space(1))) void*)g,
        (__attribute__((address_space(3))) void*)l, 16, 0, 0);
}

// ---------------------------------------------------------------------------
// Phase 1: projections via bf16 MFMA (unchanged from R6, known good).
// ---------------------------------------------------------------------------
__global__ __launch_bounds__(256) void proj_gemm_kernel(
    const float* __restrict__ x,
    const float* __restrict__ W0, const float* __restrict__ W1,
    const float* __restrict__ W2, const float* __restrict__ W3,
    const float* __restrict__ b_alpha,
    float* __restrict__ O0, float* __restrict__ O1,
    float* __restrict__ O2, float* __restrict__ O3)
{
    const int mat = blockIdx.x;
    const float* __restrict__ W = (mat == 0) ? W0 : (mat == 1) ? W1 : (mat == 2) ? W2 : W3;
    float* __restrict__ C       = (mat == 0) ? O0 : (mat == 1) ? O1 : (mat == 2) ? O2 : O3;

    const int m0   = blockIdx.y * 128;
    const int tid  = threadIdx.x;
    const int lane = tid & 63;
    const int wave = tid >> 6;
    const int ln   = lane & 15;
    const int q8   = (lane >> 4) * 8;

    __shared__ unsigned short As[128][40];
    __shared__ unsigned short Bs[64][40];

    f32x4 acc[2][4] = {};

    const int arow = tid >> 1;
    const int aseg = (tid & 1) * 16;

    float4 pa[4], pb[4];
    {
        const float* ap = &x[(size_t)(m0 + arow) * DD + aseg];
        #pragma unroll
        for (int j = 0; j < 4; j++) pa[j] = *(const float4*)(ap + 4 * j);
        if (tid < 128) {
            const float* bp = &W[(size_t)arow * DD + aseg];
            #pragma unroll
            for (int j = 0; j < 4; j++) pb[j] = *(const float4*)(bp + 4 * j);
        }
    }

    for (int k0 = 0; k0 < DD; k0 += 32) {
        __syncthreads();
        {
            unsigned short t16[16];
            const float* pf = (const float*)pa;
            #pragma unroll
            for (int j = 0; j < 16; j++) t16[j] = cvt_bf16(pf[j]);
            *(ushort8*)&As[arow][aseg]     = *(ushort8*)&t16[0];
            *(ushort8*)&As[arow][aseg + 8] = *(ushort8*)&t16[8];
            if (tid < 128) {
                const float* qf = (const float*)pb;
                #pragma unroll
                for (int j = 0; j < 16; j++) t16[j] = cvt_bf16(qf[j]);
                *(ushort8*)&Bs[arow][aseg]     = *(ushort8*)&t16[0];
                *(ushort8*)&Bs[arow][aseg + 8] = *(ushort8*)&t16[8];
            }
        }
        if (k0 + 32 < DD) {
            const float* ap = &x[(size_t)(m0 + arow) * DD + k0 + 32 + aseg];
            #pragma unroll
            for (int j = 0; j < 4; j++) pa[j] = *(const float4*)(ap + 4 * j);
            if (tid < 128) {
                const float* bp = &W[(size_t)arow * DD + k0 + 32 + aseg];
                #pragma unroll
                for (int j = 0; j < 4; j++) pb[j] = *(const float4*)(bp + 4 * j);
            }
        }
        __syncthreads();

        bfrag af[2], bf[4];
        #pragma unroll
        for (int mt = 0; mt < 2; mt++)
            af[mt] = *(const bfrag*)&As[wave * 32 + mt * 16 + ln][q8];
        #pragma unroll
        for (int nt = 0; nt < 4; nt++)
            bf[nt] = *(const bfrag*)&Bs[nt * 16 + ln][q8];
        #pragma unroll
        for (int mt = 0; mt < 2; mt++)
            #pragma unroll
            for (int nt = 0; nt < 4; nt++)
                acc[mt][nt] = __builtin_amdgcn_mfma_f32_16x16x32_bf16(
                    af[mt], bf[nt], acc[mt][nt], 0, 0, 0);
    }

    #pragma unroll
    for (int nt = 0; nt < 4; nt++) {
        const int col = nt * 16 + ln;
        const float ba = (mat == 3) ? b_alpha[col] : 0.0f;
        #pragma unroll
        for (int mt = 0; mt < 2; mt++) {
            #pragma unroll
            for (int r = 0; r < 4; r++) {
                const int row = m0 + wave * 32 + mt * 16 + (lane >> 4) * 4 + r;
                float v = acc[mt][nt][r];
                if (mat == 3) v = sigmoidf_(v + ba);
                C[(size_t)row * NN + col] = v;
            }
        }
    }
}

// ---------------------------------------------------------------------------
// Phase 2: scan -- ONE ROW-CHAIN PER WAVE, 64 lanes = 64 state columns.
// wall = T x P(per-step wave time); minimizing P means minimizing per-step
// instruction count: dot = 1 v_mul + 6-DPP wave reduction; update = 2 ops.
// grid = (B, 16 row-quads) = 128 blocks, 256 thr (4 waves = rows q*4..+4).
// k/q (shared by the block) + v/a (4-row slices) LDS-staged 32 steps at a
// time, double-buffered via global_load_lds; distance-1 register prefetch.
// ---------------------------------------------------------------------------
__global__ __launch_bounds__(256) void scan_kernel(
    const float* __restrict__ k_all, const float* __restrict__ v_all,
    const float* __restrict__ q_all, const float* __restrict__ a_all,
    const float* __restrict__ S0,
    const float* __restrict__ d_g, const float* __restrict__ b_g,
    float* __restrict__ out, float* __restrict__ S_final)
{
    const int b    = blockIdx.x;
    const int r0   = blockIdx.y * 4;
    const int tid  = threadIdx.x;
    const int lane = tid & 63;
    const int wave = tid >> 6;       // 0..3
    const int row  = r0 + wave;      // this wave's chain

    __shared__ float ks[2][CH * NN];
    __shared__ float qs[2][CH * NN];
    __shared__ float vs[2][CH * 4];
    __shared__ float as_[2][CH * 4];   // 34 KB total

    float S = S0[((size_t)b * NN + row) * NN + lane];   // S[row][lane]
    const float dg = d_g[row];
    const float bg = b_g[row];

    const int t_lane = lane >> 4;        // 0..3
    const int f_lane = (lane & 15) * 4;  // 0..60

    auto stage = [&](int chunk, int dbuf) {
        // k/q: wave w stages steps [w*8, w*8+8): 2 gll16 each (1KB = 4 steps)
        #pragma unroll
        for (int jj = 0; jj < 2; ++jj) {
            const int s0 = wave * 8 + jj * 4;
            const size_t t = (size_t)chunk * CH + s0 + t_lane;
            const size_t goff = (t * BB + b) * NN + f_lane;
            gll16(k_all + goff, &ks[dbuf][s0 * NN]);
            gll16(q_all + goff, &qs[dbuf][s0 * NN]);
        }
        // v/a: 32 steps x 4 rows = 512 B; lane l<32 -> 16B (step l, rows r0..+4)
        const size_t tv = (size_t)chunk * CH + lane;
        const size_t voff = (tv * BB + b) * NN + r0;
        if (wave == 0) { if (lane < 32) gll16(v_all + voff, &vs[dbuf][0]); }
        else if (wave == 1) { if (lane < 32) gll16(a_all + voff, &as_[dbuf][0]); }
    };

    stage(0, 0);

    float* op = out + b * NN + row;      // lane 63 stores
    const int stride = BB * NN;

    for (int c = 0; c < NCH; ++c) {
        const int cb = c & 1;
        __syncthreads();                 // chunk c staged; buf cb^1 free
        if (c + 1 < NCH) stage(c + 1, cb ^ 1);

        const float* kb = ks[cb];
        const float* qb = qs[cb];
        const float* vb = vs[cb];
        const float* ab = as_[cb];

        float kc = kb[lane];
        float qc = qb[lane];
        float vc = vb[wave];             // uniform-addr LDS read = broadcast
        float ac = ab[wave];

        #pragma unroll 4
        for (int s = 0; s < CH; ++s) {
            // distance-1 LDS prefetch (wraps, discarded on last iter)
            const int sn = (s + 1) & (CH - 1);
            const float kn = kb[sn * NN + lane];
            const float qn = qb[sn * NN + lane];
            const float vn = vb[sn * 4 + wave];
            const float an = ab[sn * 4 + wave];

            // retrieved = S[row,:]·k  (64-lane reduce, bcast from lane 63)
            const float rv = bcast63(reduce64_hi(S * kc));

            const float g    = sigmoidf_(fmaf(dg, rv, bg));
            const float coef = (1.0f - ac) * (vc * g);

            S = fmaf(ac, S, coef * kc);

            // out = S_new·q ; total valid in lanes 48-63, lane 63 stores
            const float ov = reduce64_hi(S * qc);
            const float y  = ov * ov * sigmoidf_(ov);   // out * silu(out)
            if (lane == 63) *op = y;
            op += stride;

            kc = kn; qc = qn; vc = vn; ac = an;
        }
    }

    S_final[((size_t)b * NN + row) * NN + lane] = S;
}

// ---------------------------------------------------------------------------
extern "C" void kernel_launch(void* const* d_in, const int* in_sizes, int n_in,
                              void* d_out, int out_size, void* d_ws, size_t ws_size,
                              hipStream_t stream) {
    const float* x       = (const float*)d_in[0];
    const float* S0      = (const float*)d_in[1];
    const float* W_k     = (const float*)d_in[2];
    const float* W_v     = (const float*)d_in[3];
    const float* W_q     = (const float*)d_in[4];
    const float* W_alpha = (const float*)d_in[5];
    const float* b_alpha = (const float*)d_in[6];
    const float* d_g     = (const float*)d_in[7];
    const float* b_g     = (const float*)d_in[8];
    float* out = (float*)d_out;

    const size_t arr = (size_t)TT * BB * NN;
    float* ws    = (float*)d_ws;
    float* k_all = ws;
    float* v_all = ws + arr;
    float* q_all = ws + 2 * arr;
    float* a_all = ws + 3 * arr;

    proj_gemm_kernel<<<dim3(4, TT * BB / 128), 256, 0, stream>>>(
        x, W_k, W_v, W_q, W_alpha, b_alpha, k_all, v_all, q_all, a_all);

    scan_kernel<<<dim3(BB, 16), 256, 0, stream>>>(
        k_all, v_all, q_all, a_all, S0, d_g, b_g,
        out, out + (size_t)TT * BB * NN);
}

// Round 8
// 483.724 us; speedup vs baseline: 1.1449x; 1.1449x over previous
//
#include <hip/hip_runtime.h>

#define TT 2048
#define BB 8
#define DD 1024
#define NN 64
#define CH 32              // timesteps staged per LDS chunk (scan)
#define NCH (TT / CH)

typedef __attribute__((ext_vector_type(8))) short bfrag;    // 8 bf16 (4 VGPRs)
typedef __attribute__((ext_vector_type(4))) float f32x4;    // MFMA C/D
typedef __attribute__((ext_vector_type(8))) unsigned short ushort8;

// fast sigmoid: v_exp + v_add + v_rcp (NOT the IEEE div sequence)
__device__ __forceinline__ float sigmoidf_(float x) {
    return __builtin_amdgcn_rcpf(1.0f + __expf(-x));
}

// f32 -> bf16 round-to-nearest-even
__device__ __forceinline__ unsigned short cvt_bf16(float f) {
    unsigned int u = __float_as_uint(f);
    return (unsigned short)((u + 0x7FFF + ((u >> 16) & 1)) >> 16);
}

template <int CTRL>
__device__ __forceinline__ float dpp_add(float x) {
    return x + __int_as_float(__builtin_amdgcn_update_dpp(
        0, __float_as_int(x), CTRL, 0xF, 0xF, true));
}
// Full-wave (64-lane) sum; total valid in lanes 48..63.
__device__ __forceinline__ float reduce64_hi(float x) {
    x = dpp_add<0xB1>(x);   // quad_perm xor 1
    x = dpp_add<0x4E>(x);   // quad_perm xor 2
    x = dpp_add<0x141>(x);  // row_half_mirror (xor 4)
    x = dpp_add<0x140>(x);  // row_mirror      (xor 8)
    x = dpp_add<0x142>(x);  // row_bcast15
    x = dpp_add<0x143>(x);  // row_bcast31 -> total in lanes 48..63
    return x;
}
__device__ __forceinline__ float bcast63(float x) {
    return __int_as_float(__builtin_amdgcn_readlane(__float_as_int(x), 63));
}

// async global->LDS, 16 B/lane
__device__ __forceinline__ void gll16(const float* g, float* l) {
    __builtin_amdgcn_global_load_lds(
        (const __attribute__((address_space(1))) void*)g,
        (__attribute__((address_space(3))) void*)l, 16, 0, 0);
}

// ---------------------------------------------------------------------------
// Phase 1: projections via bf16 MFMA (unchanged from R6, known good).
// ---------------------------------------------------------------------------
__global__ __launch_bounds__(256) void proj_gemm_kernel(
    const float* __restrict__ x,
    const float* __restrict__ W0, const float* __restrict__ W1,
    const float* __restrict__ W2, const float* __restrict__ W3,
    const float* __restrict__ b_alpha,
    float* __restrict__ O0, float* __restrict__ O1,
    float* __restrict__ O2, float* __restrict__ O3)
{
    const int mat = blockIdx.x;
    const float* __restrict__ W = (mat == 0) ? W0 : (mat == 1) ? W1 : (mat == 2) ? W2 : W3;
    float* __restrict__ C       = (mat == 0) ? O0 : (mat == 1) ? O1 : (mat == 2) ? O2 : O3;

    const int m0   = blockIdx.y * 128;
    const int tid  = threadIdx.x;
    const int lane = tid & 63;
    const int wave = tid >> 6;
    const int ln   = lane & 15;
    const int q8   = (lane >> 4) * 8;

    __shared__ unsigned short As[128][40];
    __shared__ unsigned short Bs[64][40];

    f32x4 acc[2][4] = {};

    const int arow = tid >> 1;
    const int aseg = (tid & 1) * 16;

    float4 pa[4], pb[4];
    {
        const float* ap = &x[(size_t)(m0 + arow) * DD + aseg];
        #pragma unroll
        for (int j = 0; j < 4; j++) pa[j] = *(const float4*)(ap + 4 * j);
        if (tid < 128) {
            const float* bp = &W[(size_t)arow * DD + aseg];
            #pragma unroll
            for (int j = 0; j < 4; j++) pb[j] = *(const float4*)(bp + 4 * j);
        }
    }

    for (int k0 = 0; k0 < DD; k0 += 32) {
        __syncthreads();
        {
            unsigned short t16[16];
            const float* pf = (const float*)pa;
            #pragma unroll
            for (int j = 0; j < 16; j++) t16[j] = cvt_bf16(pf[j]);
            *(ushort8*)&As[arow][aseg]     = *(ushort8*)&t16[0];
            *(ushort8*)&As[arow][aseg + 8] = *(ushort8*)&t16[8];
            if (tid < 128) {
                const float* qf = (const float*)pb;
                #pragma unroll
                for (int j = 0; j < 16; j++) t16[j] = cvt_bf16(qf[j]);
                *(ushort8*)&Bs[arow][aseg]     = *(ushort8*)&t16[0];
                *(ushort8*)&Bs[arow][aseg + 8] = *(ushort8*)&t16[8];
            }
        }
        if (k0 + 32 < DD) {
            const float* ap = &x[(size_t)(m0 + arow) * DD + k0 + 32 + aseg];
            #pragma unroll
            for (int j = 0; j < 4; j++) pa[j] = *(const float4*)(ap + 4 * j);
            if (tid < 128) {
                const float* bp = &W[(size_t)arow * DD + k0 + 32 + aseg];
                #pragma unroll
                for (int j = 0; j < 4; j++) pb[j] = *(const float4*)(bp + 4 * j);
            }
        }
        __syncthreads();

        bfrag af[2], bf[4];
        #pragma unroll
        for (int mt = 0; mt < 2; mt++)
            af[mt] = *(const bfrag*)&As[wave * 32 + mt * 16 + ln][q8];
        #pragma unroll
        for (int nt = 0; nt < 4; nt++)
            bf[nt] = *(const bfrag*)&Bs[nt * 16 + ln][q8];
        #pragma unroll
        for (int mt = 0; mt < 2; mt++)
            #pragma unroll
            for (int nt = 0; nt < 4; nt++)
                acc[mt][nt] = __builtin_amdgcn_mfma_f32_16x16x32_bf16(
                    af[mt], bf[nt], acc[mt][nt], 0, 0, 0);
    }

    #pragma unroll
    for (int nt = 0; nt < 4; nt++) {
        const int col = nt * 16 + ln;
        const float ba = (mat == 3) ? b_alpha[col] : 0.0f;
        #pragma unroll
        for (int mt = 0; mt < 2; mt++) {
            #pragma unroll
            for (int r = 0; r < 4; r++) {
                const int row = m0 + wave * 32 + mt * 16 + (lane >> 4) * 4 + r;
                float v = acc[mt][nt][r];
                if (mat == 3) v = sigmoidf_(v + ba);
                C[(size_t)row * NN + col] = v;
            }
        }
    }
}

// ---------------------------------------------------------------------------
// Phase 1.5: prep. w = (1-alpha)*v (in-place over v_all); kq[t,b] = k_t . q_t.
// grid = TT*BB/4 blocks x 256 (4 waves); wave handles one (t,b) pair.
// ---------------------------------------------------------------------------
__global__ __launch_bounds__(256) void prep_kernel(
    const float* __restrict__ k_all, float* __restrict__ v_all,
    const float* __restrict__ q_all, const float* __restrict__ a_all,
    float* __restrict__ kq_all)
{
    const int tid  = threadIdx.x;
    const int lane = tid & 63;
    const int wave = tid >> 6;
    const size_t tb = (size_t)blockIdx.x * 4 + wave;
    const size_t off = tb * NN + lane;

    const float vv = v_all[off];
    const float aa = a_all[off];
    v_all[off] = (1.0f - aa) * vv;

    const float kq = reduce64_hi(k_all[off] * q_all[off]);
    if (lane == 63) kq_all[tb] = kq;
}

// ---------------------------------------------------------------------------
// Phase 2: scan -- one row-chain per wave, 64 lanes = 64 state columns.
// Serial step reduced to: 2 muls + 2 parallel DPP reductions + 1 sigmoid
// (rcp form) + 3 fma/mul. out = S_t.q folded as alpha*(S.q) + coef*(k.q)
// with kq precomputed per chunk (parallel pre-pass); y=silu deferred to a
// per-chunk epilogue. grid = (B, 8) = 64 blocks x 512 thr (8 waves = rows
// r0..r0+8; 2 waves/SIMD for chain-latency hiding).
// ---------------------------------------------------------------------------
__global__ __launch_bounds__(512) void scan_kernel(
    const float* __restrict__ k_all, const float* __restrict__ w_all,
    const float* __restrict__ q_all, const float* __restrict__ a_all,
    const float* __restrict__ kq_all,
    const float* __restrict__ S0,
    const float* __restrict__ d_g, const float* __restrict__ b_g,
    float* __restrict__ out, float* __restrict__ S_final)
{
    const int b    = blockIdx.x;
    const int r0   = blockIdx.y * 8;
    const int tid  = threadIdx.x;
    const int lane = tid & 63;
    const int wave = tid >> 6;       // 0..7
    const int row  = r0 + wave;

    __shared__ float ks[2][CH * NN];
    __shared__ float qs[2][CH * NN];
    __shared__ float asl[2][CH * 8];
    __shared__ float wsl[2][CH * 8];
    __shared__ float kql[CH];
    __shared__ float ovb[8][CH];     // ~38 KB total

    float S = S0[((size_t)b * NN + row) * NN + lane];
    // sigmoid arg negated form: exp(-(dg*rv+bg))
    const float ndg = -d_g[row];
    const float nbg = -b_g[row];

    const int t_lane = lane >> 4;        // 0..3
    const int f_lane = (lane & 15) * 4;  // 0..60

    auto stage = [&](int chunk, int dbuf) {
        // k/q: wave w stages steps [4w, 4w+4): one gll16 per array
        const int s0 = wave * 4;
        const size_t t = (size_t)chunk * CH + s0 + t_lane;
        const size_t goff = (t * BB + b) * NN + f_lane;
        gll16(k_all + goff, &ks[dbuf][s0 * NN]);
        gll16(q_all + goff, &qs[dbuf][s0 * NN]);
        // alpha/w 8-row slices: lane l -> step l>>1, rows r0+(l&1)*4..+4
        const size_t tv = (size_t)chunk * CH + (lane >> 1);
        const size_t voff = (tv * BB + b) * NN + r0 + (lane & 1) * 4;
        if (wave == 0)      gll16(a_all + voff, &asl[dbuf][0]);
        else if (wave == 1) gll16(w_all + voff, &wsl[dbuf][0]);
    };

    stage(0, 0);

    for (int c = 0; c < NCH; ++c) {
        const int cb = c & 1;
        __syncthreads();                 // chunk c staged; buf cb^1 free
        if (c + 1 < NCH) stage(c + 1, cb ^ 1);

        const float* kb = ks[cb];
        const float* qb = qs[cb];
        const float* ab = asl[cb];
        const float* wb = wsl[cb];

        // kq pre-pass (parallel): wave w computes steps [4w, 4w+4)
        #pragma unroll
        for (int j = 0; j < 4; ++j) {
            const int s = wave * 4 + j;
            const float t = reduce64_hi(kb[s * NN + lane] * qb[s * NN + lane]);
            if (lane == 63) kql[s] = t;
        }
        __syncthreads();                 // kql ready

        float kc = kb[lane];
        float qc = qb[lane];
        float ac = ab[wave];
        float wc = wb[wave];
        float kqc = kql[0];

        #pragma unroll 4
        for (int s = 0; s < CH; ++s) {
            // distance-1 prefetch (wraps, discarded on last iter)
            const int sn = (s + 1) & (CH - 1);
            const float kn  = kb[sn * NN + lane];
            const float qn  = qb[sn * NN + lane];
            const float an  = ab[sn * 8 + wave];
            const float wn  = wb[sn * 8 + wave];
            const float kqn = kql[sn];

            const float m1 = S * kc;     // -> retrieved
            const float m2 = S * qc;     // -> S_{t-1}.q (independent chain)
            const float rv = bcast63(reduce64_hi(m1));
            const float dv = bcast63(reduce64_hi(m2));

            const float g    = __builtin_amdgcn_rcpf(
                1.0f + __expf(fmaf(ndg, rv, nbg)));
            const float coef = wc * g;           // (1-a)*v*g

            S = fmaf(ac, S, coef * kc);
            const float ov = fmaf(ac, dv, coef * kqc);   // S_t . q
            ovb[wave][s] = ov;                   // uniform value, any lane

            kc = kn; qc = qn; ac = an; wc = wn; kqc = kqn;
        }

        // y epilogue: lanes 0..31 handle one step each (wave-private buffer)
        if (lane < CH) {
            const float ovv = ovb[wave][lane];
            const float y = ovv * ovv * sigmoidf_(ovv);  // out * silu(out)
            out[((size_t)(c * CH + lane) * BB + b) * NN + row] = y;
        }
    }

    S_final[((size_t)b * NN + row) * NN + lane] = S;
}

// ---------------------------------------------------------------------------
extern "C" void kernel_launch(void* const* d_in, const int* in_sizes, int n_in,
                              void* d_out, int out_size, void* d_ws, size_t ws_size,
                              hipStream_t stream) {
    const float* x       = (const float*)d_in[0];
    const float* S0      = (const float*)d_in[1];
    const float* W_k     = (const float*)d_in[2];
    const float* W_v     = (const float*)d_in[3];
    const float* W_q     = (const float*)d_in[4];
    const float* W_alpha = (const float*)d_in[5];
    const float* b_alpha = (const float*)d_in[6];
    const float* d_g     = (const float*)d_in[7];
    const float* b_g     = (const float*)d_in[8];
    float* out = (float*)d_out;

    const size_t arr = (size_t)TT * BB * NN;
    float* ws     = (float*)d_ws;
    float* k_all  = ws;
    float* v_all  = ws + arr;        // becomes w = (1-alpha)*v after prep
    float* q_all  = ws + 2 * arr;
    float* a_all  = ws + 3 * arr;
    float* kq_all = ws + 4 * arr;    // TT*BB floats (64 KB)

    proj_gemm_kernel<<<dim3(4, TT * BB / 128), 256, 0, stream>>>(
        x, W_k, W_v, W_q, W_alpha, b_alpha, k_all, v_all, q_all, a_all);

    prep_kernel<<<dim3(TT * BB / 4), 256, 0, stream>>>(
        k_all, v_all, q_all, a_all, kq_all);

    scan_kernel<<<dim3(BB, 8), 512, 0, stream>>>(
        k_all, v_all, q_all, a_all, kq_all, S0, d_g, b_g,
        out, out + (size_t)TT * BB * NN);
}